// Round 9
// baseline (145.927 us; speedup 1.0000x reference)
//
#include <hip/hip_runtime.h>
#include <hip/hip_bf16.h>

#define NROW 50000
#define DIN 128
#define DM 256
#define HH 4
#define NC 40
#define BHN 200000
#define NBLK 1563  // ceil(50000/32): 32 rows per 1-wave block (2 row-tiles)

typedef float f32x4 __attribute__((ext_vector_type(4)));
typedef short bf16x8 __attribute__((ext_vector_type(8)));

__device__ __forceinline__ unsigned int pk2(float lo, float hi) {
    __hip_bfloat162 h = __float22bfloat162_rn(make_float2(lo, hi));
    return *(unsigned int*)&h;
}

// -------- prep: [0,196) scatter x4 | [196,212) Wpk | [212,224) Wgpk | [224,264) bias2+wsum --------
// Wpk  [kc][t][ln][8]: fragment-packed Win^T (A operand of swapped phase-1 MFMA).
// Wgpk [h][kc][t][ln][8]: fragment-packed gamma*Wh^T, pi-permuted k so the phase-3
//   A-fragment equals the lane-local packed Y words in natural order.
__global__ __launch_bounds__(256) void k_prep(const int* __restrict__ pi,
                                              const float* __restrict__ pv,
                                              const float* __restrict__ Win,
                                              const float* __restrict__ Wh,
                                              const float* __restrict__ gamma,
                                              const float* __restrict__ beta,
                                              const float* __restrict__ bh,
                                              float* __restrict__ vcol,
                                              unsigned short* __restrict__ Wpk,
                                              unsigned short* __restrict__ Wgpk,
                                              float* __restrict__ bias2,
                                              float* __restrict__ wsum) {
    const int bid = blockIdx.x, tid = threadIdx.x;
    if (bid < 196) {
        // vectorized scatter: 4 elements/thread; 50000%4==0 so the 4-group
        // never straddles a batch boundary -> one b for all 4.
        int k4 = (bid * 256 + tid) * 4;
        if (k4 < BHN) {
            int4   c4 = *(const int4*)&pi[2 * BHN + k4];
            float4 v4 = *(const float4*)&pv[k4];
            int b = (k4 >= 150000) ? 3 : (k4 >= 100000) ? 2 : (k4 >= 50000) ? 1 : 0;
            float* vb = vcol + b * NROW;
            vb[c4.x] = v4.x; vb[c4.y] = v4.y; vb[c4.z] = v4.z; vb[c4.w] = v4.w;
        }
    } else if (bid < 212) {
        int base = (bid - 196) * 512;
        #pragma unroll
        for (int qq = 0; qq < 2; ++qq) {
            int s = base + qq * 256 + tid;
            int ln = s & 63;
            int t  = (s >> 6) & 15;
            int kc = s >> 10;
            int n  = t * 16 + (ln & 15);
            int kb = kc * 32 + ((ln >> 4) << 3);
            union { unsigned int ui[4]; uint4 v4; } u;
            #pragma unroll
            for (int jj = 0; jj < 4; ++jj)
                u.ui[jj] = pk2(Win[(kb + 2 * jj) * DM + n], Win[(kb + 2 * jj + 1) * DM + n]);
            *(uint4*)&Wpk[s * 8] = u.v4;
        }
    } else if (bid < 224) {
        int base = (bid - 212) * 512;
        #pragma unroll
        for (int qq = 0; qq < 2; ++qq) {
            int s = base + qq * 256 + tid;
            int ln = s & 63;
            int u6 = s >> 6;
            int t  = u6 % 3;
            int v6 = u6 / 3;
            int kc = v6 & 7;
            int h  = v6 >> 3;
            int c  = t * 16 + (ln & 15);
            int dbase = h * 256 + kc * 32 + ((ln >> 4) << 2);   // h*256 + 32*kc + 4*q
            union { unsigned int ui[4]; uint4 v4; } u;
            if (c < NC) {
                #pragma unroll
                for (int jj = 0; jj < 4; ++jj) {
                    int dA = dbase + ((jj >> 1) << 4) + ((jj & 1) << 1);  // pi row for k-slot 2jj
                    u.ui[jj] = pk2(gamma[dA] * Wh[dA * NC + c],
                                   gamma[dA + 1] * Wh[(dA + 1) * NC + c]);
                }
            } else {
                u.v4 = make_uint4(0u, 0u, 0u, 0u);
            }
            *(uint4*)&Wgpk[s * 8] = u.v4;
        }
    } else {   // bias2[c] = bh[c] + sum_d beta[d]*Wh[d][c] ; wsum[c] = sum_d gamma[d]*Wh[d][c]
        __shared__ float redb[256], redw[256];
        int c = bid - 224;
        float sb = 0.f, sw = 0.f;
        #pragma unroll
        for (int q = 0; q < 4; ++q) {
            int d = tid + 256 * q;
            float w = Wh[d * NC + c];
            sb = fmaf(beta[d], w, sb);
            sw = fmaf(gamma[d], w, sw);
        }
        redb[tid] = sb; redw[tid] = sw;
        __syncthreads();
        for (int st = 128; st > 0; st >>= 1) {
            if (tid < st) { redb[tid] += redb[tid + st]; redw[tid] += redw[tid + st]; }
            __syncthreads();
        }
        if (tid == 0) { bias2[c] = bh[c] + redb[0]; wsum[c] = redw[0]; }
    }
}

// y-pass for one row-tile/head: y once (f32), LN stats inline, pack to bf16 ya[]
// (A-fragment order via pi-perm). bias from LDS (runtime half -> LDS addr, fine).
#define Y_PASS(VH, ACC, S, SS) { \
    _Pragma("unroll") \
    for (int tt = 0; tt < 8; ++tt) { \
        float4 b4 = *(const float4*)&bshm[half * 128 + tt * 16 + quad * 4]; \
        float y0 = (VH) * fmaxf(fmaf((VH), ACC[tt][0], b4.x), 0.f); \
        float y1 = (VH) * fmaxf(fmaf((VH), ACC[tt][1], b4.y), 0.f); \
        float y2 = (VH) * fmaxf(fmaf((VH), ACC[tt][2], b4.z), 0.f); \
        float y3 = (VH) * fmaxf(fmaf((VH), ACC[tt][3], b4.w), 0.f); \
        S += (y0 + y1) + (y2 + y3); \
        SS = fmaf(y0, y0, SS); SS = fmaf(y1, y1, SS); \
        SS = fmaf(y2, y2, SS); SS = fmaf(y3, y3, SS); \
        ya[tt * 2]     = pk2(y0, y1); \
        ya[tt * 2 + 1] = pk2(y2, y3); \
    } }

// 12 MFMAs for one row-tile's head chunk from the SHARED wg fragments.
#define HEAD_MFMA(ACCO) { \
    _Pragma("unroll") \
    for (int kcr = 0; kcr < 4; ++kcr) { \
        union { unsigned int ui[4]; bf16x8 v; } af; \
        af.ui[0] = ya[4 * kcr];     af.ui[1] = ya[4 * kcr + 1]; \
        af.ui[2] = ya[4 * kcr + 2]; af.ui[3] = ya[4 * kcr + 3]; \
        _Pragma("unroll") \
        for (int t3 = 0; t3 < 3; ++t3) \
            ACCO[t3] = __builtin_amdgcn_mfma_f32_16x16x32_bf16( \
                af.v, wg[kcr * 3 + t3], ACCO[t3], 0, 0, 0); \
    } }

// -------- fused, LOOPED SMALL BODY (R8 post-mortem: four unrolled variants,
// ~25-30KB straight-line bodies, all plateau 48-58us with every pipe <25% busy
// and models underpredicting 4x; more waves/CU made it WORSE (R7 vs R8) -> not
// latency-bound. Shared invariant = code footprint >= I$ capacity: ~6 staggered
// waves/CU each stream the whole body once -> every I-fetch is a capacity miss.
// This version: identical data structure to R8 (2 row-tiles/wave, direct-to-reg
// weight loads, no barriers) but real loops over half/kc/h -> ~5KB body.
// Rule #20 honored: register arrays indexed ONLY by fully-unrolled inner vars;
// runtime half/kc/h appear only in addresses. accG zeroed per half (no kc==0
// select). Grid/launch identical to R8: single-variable test of code size. --------
__global__ __launch_bounds__(64, 2) void k_fused(
    const float* __restrict__ feats, const float* __restrict__ appd,
    const unsigned short* __restrict__ Wpk,
    const unsigned short* __restrict__ Wgpk,
    const float* __restrict__ vcol,
    const float* __restrict__ b_in,
    const float* __restrict__ bias2,
    const float* __restrict__ wsum,
    float* __restrict__ out)
{
    __shared__ __align__(16) float bshm[256];               // b_in, LDS-resident

    const int tid = threadIdx.x;                            // = lane, 0..63
    const int ln = tid;
    const int quad = ln >> 4;
    const int lr = ln & 15;
    const int jw = blockIdx.x * 32;
    const int ar0 = min(jw + lr, NROW - 1);
    const int ar1 = min(jw + 16 + lr, NROW - 1);

    #pragma unroll
    for (int q = 0; q < 4; ++q) bshm[tid + 64 * q] = b_in[tid + 64 * q];
    __syncthreads();                              // intra-wave only (1 wave/block)

    // per-lane bases
    const unsigned short* wpL = Wpk  + (size_t)ln * 8;
    const unsigned short* wgL = Wgpk + (size_t)ln * 8;
    const float* f0 = feats + (size_t)ar0 * DIN;
    const float* a0 = appd  + (size_t)ar0 * DIN;
    const float* f1 = feats + (size_t)ar1 * DIN;
    const float* a1 = appd  + (size_t)ar1 * DIN;

    const f32x4 zero4 = {0.f, 0.f, 0.f, 0.f};
    float s0 = 0.f, ss0 = 0.f, s1 = 0.f, ss1 = 0.f;
    f32x4 accO0[3], accO1[3];
    #pragma unroll
    for (int t = 0; t < 3; ++t) { accO0[t] = zero4; accO1[t] = zero4; }

    #pragma unroll 1
    for (int half = 0; half < 2; ++half) {
        f32x4 accG0[8], accG1[8];
        #pragma unroll
        for (int t = 0; t < 8; ++t) { accG0[t] = zero4; accG1[t] = zero4; }

        // ---- phase 1 (this half): G cols [half*128, +128). 8 weight frags/kc
        // feed 16 MFMAs (both row-tiles); feats loaded per-kc (no long-lived afr).
        #pragma unroll 2
        for (int kc = 0; kc < 8; ++kc) {
            const float* s0p = (kc < 4) ? f0 : a0;
            const float* s1p = (kc < 4) ? f1 : a1;
            const int ko = (kc & 3) * 32 + quad * 8;
            float4 x0 = *(const float4*)(s0p + ko);
            float4 x1 = *(const float4*)(s0p + ko + 4);
            float4 z0 = *(const float4*)(s1p + ko);
            float4 z1 = *(const float4*)(s1p + ko + 4);
            bf16x8 wf[8];
            #pragma unroll
            for (int th = 0; th < 8; ++th)
                wf[th] = *(const bf16x8*)&wpL[(size_t)(kc * 16 + half * 8 + th) * 512];
            union { unsigned int ui[4]; bf16x8 v; } av0, av1;
            av0.ui[0] = pk2(x0.x, x0.y); av0.ui[1] = pk2(x0.z, x0.w);
            av0.ui[2] = pk2(x1.x, x1.y); av0.ui[3] = pk2(x1.z, x1.w);
            av1.ui[0] = pk2(z0.x, z0.y); av1.ui[1] = pk2(z0.z, z0.w);
            av1.ui[2] = pk2(z1.x, z1.y); av1.ui[3] = pk2(z1.z, z1.w);
            #pragma unroll
            for (int th = 0; th < 8; ++th) {
                accG0[th] = __builtin_amdgcn_mfma_f32_16x16x32_bf16(wf[th], av0.v, accG0[th], 0, 0, 0);
                accG1[th] = __builtin_amdgcn_mfma_f32_16x16x32_bf16(wf[th], av1.v, accG1[th], 0, 0, 0);
            }
        }

        // ---- phase 2+3 (this half), per head: ONE 12-frag wg set serves both
        // row-tiles (24 MFMAs + 2 Y_PASSes); vcol loaded per-iteration.
        #pragma unroll 1
        for (int h = 0; h < HH; ++h) {
            bf16x8 wg[12];
            #pragma unroll
            for (int kcr = 0; kcr < 4; ++kcr)
                #pragma unroll
                for (int t3 = 0; t3 < 3; ++t3)
                    wg[kcr * 3 + t3] = *(const bf16x8*)
                        &wgL[(size_t)(((h * 8 + half * 4 + kcr) * 3 + t3)) * 512];
            const float vh0 = vcol[h * NROW + ar0];
            const float vh1 = vcol[h * NROW + ar1];
            unsigned int ya[16];
            Y_PASS(vh0, accG0, s0, ss0)           // hides wg/vcol latency
            HEAD_MFMA(accO0)
            Y_PASS(vh1, accG1, s1, ss1)           // overlaps rt0's MFMAs
            HEAD_MFMA(accO1)
        }
    }

    // ---- epilogue per row-tile: finish LN stats, fold affine:
    // out = rs*acc + nm*wsum + bias2
    s0  += __shfl_xor(s0, 16);  s0  += __shfl_xor(s0, 32);
    ss0 += __shfl_xor(ss0, 16); ss0 += __shfl_xor(ss0, 32);
    s1  += __shfl_xor(s1, 16);  s1  += __shfl_xor(s1, 32);
    ss1 += __shfl_xor(ss1, 16); ss1 += __shfl_xor(ss1, 32);
    float mm0  = s0 * (1.f / 1024.f);
    float rs0  = rsqrtf(ss0 * (1.f / 1024.f) - mm0 * mm0 + 1e-5f);
    float nm0  = -mm0 * rs0;
    float mm1  = s1 * (1.f / 1024.f);
    float rs1  = rsqrtf(ss1 * (1.f / 1024.f) - mm1 * mm1 + 1e-5f);
    float nm1  = -mm1 * rs1;

    float rs_r0[4], nm_r0[4], rs_r1[4], nm_r1[4];
    #pragma unroll
    for (int rg = 0; rg < 4; ++rg) {
        int rloc = quad * 4 + rg;                 // lane rloc (quad 0, lr=rloc) has row jw+rloc
        rs_r0[rg] = __shfl(rs0, rloc);
        nm_r0[rg] = __shfl(nm0, rloc);
        rs_r1[rg] = __shfl(rs1, rloc);
        nm_r1[rg] = __shfl(nm1, rloc);
    }
    #pragma unroll
    for (int t = 0; t < 3; ++t) {
        int c = t * 16 + lr;
        if (c < NC) {
            float w2 = wsum[c], b2 = bias2[c];
            #pragma unroll
            for (int rg = 0; rg < 4; ++rg) {
                int row0 = jw + quad * 4 + rg;
                int row1 = row0 + 16;
                if (row0 < NROW)
                    out[(size_t)row0 * NC + c] = fmaf(rs_r0[rg], accO0[t][rg], fmaf(nm_r0[rg], w2, b2));
                if (row1 < NROW)
                    out[(size_t)row1 * NC + c] = fmaf(rs_r1[rg], accO1[t][rg], fmaf(nm_r1[rg], w2, b2));
            }
        }
    }
}

extern "C" void kernel_launch(void* const* d_in, const int* in_sizes, int n_in,
                              void* d_out, int out_size, void* d_ws, size_t ws_size,
                              hipStream_t stream) {
    const int*   pi    = (const int*)d_in[0];
    const float* pv    = (const float*)d_in[1];
    const float* feats = (const float*)d_in[2];
    const float* appd  = (const float*)d_in[3];
    const float* Win   = (const float*)d_in[4];
    const float* b_in  = (const float*)d_in[5];
    const float* gamma = (const float*)d_in[6];
    const float* beta  = (const float*)d_in[7];
    const float* Wh    = (const float*)d_in[8];
    const float* bh    = (const float*)d_in[9];
    float* out = (float*)d_out;

    char* w = (char*)d_ws;
    float*          vcolW  = (float*)w;                        // 800000 B
    unsigned short* WpkW   = (unsigned short*)(w + 800000);    // 131072 B
    unsigned short* WgpkW  = (unsigned short*)(w + 931072);    // 98304 B
    float*          bias2W = (float*)(w + 1029376);            // 160 B
    float*          wsumW  = (float*)(w + 1029536);            // 160 B

    k_prep<<<264, 256, 0, stream>>>(pi, pv, Win, Wh, gamma, beta, bh,
                                    vcolW, WpkW, WgpkW, bias2W, wsumW);
    k_fused<<<NBLK, 64, 0, stream>>>(feats, appd, WpkW, WgpkW, vcolW, b_in,
                                     bias2W, wsumW, out);
}